// Round 5
// baseline (509.792 us; speedup 1.0000x reference)
//
#include <hip/hip_runtime.h>
#include <hip/hip_bf16.h>
#include <math.h>

typedef __hip_bfloat16 bf16;
typedef __bf16 bf16x8 __attribute__((ext_vector_type(8)));
typedef float floatx4 __attribute__((ext_vector_type(4)));

#define CSR_CH  4096

__device__ __forceinline__ unsigned short f2bu(float f) {
    bf16 b = __float2bfloat16(f);
    return __builtin_bit_cast(unsigned short, b);
}
__device__ __forceinline__ float bu2f(unsigned short u) {
    return __uint_as_float(((unsigned)u) << 16);
}

// accumulate 8 bf16 (packed in uint4) scaled by w into ac[0..7]
__device__ __forceinline__ void accu4(float* ac, float w, uint4 u) {
    ac[0] += w * __uint_as_float(u.x << 16);
    ac[1] += w * __uint_as_float(u.x & 0xffff0000u);
    ac[2] += w * __uint_as_float(u.y << 16);
    ac[3] += w * __uint_as_float(u.y & 0xffff0000u);
    ac[4] += w * __uint_as_float(u.z << 16);
    ac[5] += w * __uint_as_float(u.z & 0xffff0000u);
    ac[6] += w * __uint_as_float(u.w << 16);
    ac[7] += w * __uint_as_float(u.w & 0xffff0000u);
}
// accumulate 4 bf16 (packed in uint2) scaled by w into ac[0..3]
__device__ __forceinline__ void accu2(float* ac, float w, uint2 u) {
    ac[0] += w * __uint_as_float(u.x << 16);
    ac[1] += w * __uint_as_float(u.x & 0xffff0000u);
    ac[2] += w * __uint_as_float(u.y << 16);
    ac[3] += w * __uint_as_float(u.y & 0xffff0000u);
}

__device__ __forceinline__ float lrelu_exp(float lg) {
    lg = lg > 0.f ? lg : 0.2f * lg;
    return __expf(lg);
}

// ====== MFMA GEMM + fused alpha (+ optional per-dst hist blocks) ============
// blocks [0,NG): GEMM; blocks [NG, NG+NBLK): per-dst histogram (global atomics
// into cnt[d]; cnt zeroed via hipMemsetAsync before launch).
template<typename XT, int H>
__global__ __launch_bounds__(256) void gemm_mfma(
    const XT* __restrict__ X, const float* __restrict__ W,
    const float* __restrict__ a_src, const float* __restrict__ a_dst,
    bf16* __restrict__ Hout, float* __restrict__ asrc, float* __restrict__ adst,
    int N, int NG, const int* __restrict__ ei, int E,
    int* __restrict__ cnt)
{
    constexpr int M = H * 16;
    constexpr int KP = 136;
    constexpr int NT = M / 16;
    constexpr int HPQ = H / 4;
    __shared__ __align__(16) unsigned short Wt[M * KP];
    __shared__ __align__(16) unsigned short As[64 * KP];
    __shared__ float As_s[M], Ad_s[M];
    int tid = threadIdx.x;

    if (blockIdx.x >= NG) {          // ---- per-dst hist path ----
        int blk = blockIdx.x - NG;
        int e0 = blk * CSR_CH;
        int e1 = min(E, e0 + CSR_CH);
        for (int e = e0 + tid; e < e1; e += 256)
            atomicAdd(&cnt[ei[E + e]], 1);
        return;
    }

    int r0 = blockIdx.x * 64;
    for (int i = tid; i < M; i += 256) { As_s[i] = a_src[i]; Ad_s[i] = a_dst[i]; }
    for (int idx = tid; idx < 128 * M; idx += 256) {
        int k = idx / M, m = idx % M;
        Wt[m * KP + k] = f2bu(W[idx]);
    }
    if constexpr (__is_same(XT, float)) {
        for (int idx = tid; idx < 64 * 32; idx += 256) {
            int row = idx >> 5, c4 = (idx & 31) * 4;
            int grow = r0 + row;
            float4 v = make_float4(0.f, 0.f, 0.f, 0.f);
            if (grow < N)
                v = *reinterpret_cast<const float4*>(X + (size_t)grow * 128 + c4);
            unsigned short* a = &As[row * KP + c4];
            a[0] = f2bu(v.x); a[1] = f2bu(v.y); a[2] = f2bu(v.z); a[3] = f2bu(v.w);
        }
    } else {
        for (int idx = tid; idx < 64 * 16; idx += 256) {
            int row = idx >> 4, c8 = (idx & 15) * 8;
            int grow = r0 + row;
            uint4 v = make_uint4(0u, 0u, 0u, 0u);
            if (grow < N)
                v = *reinterpret_cast<const uint4*>((const unsigned short*)X + (size_t)grow * 128 + c8);
            *reinterpret_cast<uint4*>(&As[row * KP + c8]) = v;
        }
    }
    __syncthreads();

    int w = tid >> 6, l = tid & 63, q = l >> 4, c = l & 15;
    floatx4 acc[NT];
    #pragma unroll
    for (int t = 0; t < NT; ++t) acc[t] = (floatx4){0.f, 0.f, 0.f, 0.f};

    #pragma unroll
    for (int kc = 0; kc < 4; ++kc) {
        bf16x8 a = *reinterpret_cast<const bf16x8*>(&As[(w * 16 + c) * KP + kc * 32 + q * 8]);
        #pragma unroll
        for (int t = 0; t < NT; ++t) {
            bf16x8 b = *reinterpret_cast<const bf16x8*>(&Wt[(t * 16 + c) * KP + kc * 32 + q * 8]);
            acc[t] = __builtin_amdgcn_mfma_f32_16x16x32_bf16(a, b, acc[t], 0, 0, 0);
        }
    }
    __syncthreads();
    #pragma unroll
    for (int t = 0; t < NT; ++t)
        #pragma unroll
        for (int r = 0; r < 4; ++r)
            As[(w * 16 + q * 4 + r) * KP + t * 16 + c] = f2bu(acc[t][r]);
    __syncthreads();
    for (int idx = tid; idx < 64 * (M / 8); idx += 256) {
        int row = idx / (M / 8), g = idx % (M / 8);
        int grow = r0 + row;
        if (grow < N)
            *reinterpret_cast<uint4*>(Hout + (size_t)grow * M + g * 8) =
                *reinterpret_cast<const uint4*>(&As[row * KP + g * 8]);
    }
    {
        int r = tid >> 2, qq = tid & 3;
        int grow = r0 + r;
        if (grow < N) {
            #pragma unroll
            for (int hh = 0; hh < HPQ; ++hh) {
                int hd = qq * HPQ + hh;
                float s1 = 0.f, s2 = 0.f;
                #pragma unroll
                for (int f = 0; f < 16; f += 2) {
                    unsigned u = *reinterpret_cast<const unsigned*>(&As[r * KP + hd * 16 + f]);
                    float v0 = __uint_as_float(u << 16);
                    float v1 = __uint_as_float(u & 0xffff0000u);
                    s1 += v0 * As_s[hd * 16 + f] + v1 * As_s[hd * 16 + f + 1];
                    s2 += v0 * Ad_s[hd * 16 + f] + v1 * Ad_s[hd * 16 + f + 1];
                }
                asrc[(size_t)grow * H + hd] = s1;
                adst[(size_t)grow * H + hd] = s2;
            }
        }
    }
}

// ============== direct per-dst CSR build ====================================
// scanA: per-chunk reduce of cnt -> bsum
__global__ __launch_bounds__(256) void csr_scanA(
    const int* __restrict__ cnt, int N, int* __restrict__ bsum)
{
    __shared__ int sm[256];
    int b = blockIdx.x, t = threadIdx.x, i = b * 256 + t;
    sm[t] = (i < N) ? cnt[i] : 0;
    __syncthreads();
    #pragma unroll
    for (int o = 128; o > 0; o >>= 1) {
        if (t < o) sm[t] += sm[t + o];
        __syncthreads();
    }
    if (t == 0) bsum[b] = sm[0];
}

// scanB: exclusive scan of bsum (NCH <= 512)
__global__ __launch_bounds__(512) void csr_scanB(
    const int* __restrict__ bsum, int NCH, int* __restrict__ boff)
{
    __shared__ int sm[512];
    int t = threadIdx.x;
    sm[t] = (t < NCH) ? bsum[t] : 0;
    __syncthreads();
    #pragma unroll
    for (int o = 1; o < 512; o <<= 1) {
        int x = (t >= o) ? sm[t - o] : 0;
        __syncthreads();
        sm[t] += x;
        __syncthreads();
    }
    if (t < NCH) boff[t] = (t == 0) ? 0 : sm[t - 1];
}

// scanC: per-chunk exclusive scan + boff -> per-dst start; writes off + ptrSE
__global__ __launch_bounds__(256) void csr_scanC(
    const int* __restrict__ cnt, const int* __restrict__ boff, int N,
    int* __restrict__ off, int2* __restrict__ ptrSE)
{
    __shared__ int sm[256];
    int b = blockIdx.x, t = threadIdx.x, i = b * 256 + t;
    int v = (i < N) ? cnt[i] : 0;
    sm[t] = v;
    __syncthreads();
    #pragma unroll
    for (int o = 1; o < 256; o <<= 1) {
        int x = (t >= o) ? sm[t - o] : 0;
        __syncthreads();
        sm[t] += x;
        __syncthreads();
    }
    if (i < N) {
        int start = boff[b] + sm[t] - v;
        off[i] = start;
        ptrSE[i] = make_int2(start, start + v);
    }
}

// scatter: one pass over edges, direct col placement via off[d] atomics
__global__ __launch_bounds__(256) void csr_scatter(
    const int* __restrict__ ei, int E,
    int* __restrict__ off, int* __restrict__ col)
{
    int idx = blockIdx.x * 256 + threadIdx.x;
    int stride = gridDim.x * 256;
    for (int e = idx; e < E; e += stride) {
        int s = ei[e];
        int d = ei[E + e];
        int pos = atomicAdd(&off[d], 1);
        col[pos] = s;
    }
}

// ------- layer-1 CSR agg + bias + LN + ELU: 16-lane subgroup per dst --------
// Depth-1 pipeline: cols fetched 2 groups ahead, asrc+row data 1 group ahead.
__global__ __launch_bounds__(256) void agg_ln_l1(
    const int2* __restrict__ ptrSE, const int* __restrict__ col,
    const float* __restrict__ asrc, const float* __restrict__ adst,
    const bf16* __restrict__ hb, const float* __restrict__ bias,
    const float* __restrict__ g, const float* __restrict__ be,
    bf16* __restrict__ out, int N)
{
    int tid = threadIdx.x;
    int sub = tid >> 4, j = tid & 15;
    int d = blockIdx.x * 16 + sub;
    if (d >= N) return;
    int f0 = j * 8;
    int hd = j >> 1;                  // H=8: 2 lanes per head
    int2 se = ptrSE[d];
    int e = se.x, end = se.y;
    float adst_h = adst[d * 8 + hd];
    const unsigned short* hw = (const unsigned short*)hb;
    const unsigned short* hwl = hw + f0;
    const float* as_h = asrc + hd;

    float ac[8];
    #pragma unroll
    for (int p = 0; p < 8; ++p) ac[p] = 0.f;
    float dn;

    {   // self loop
        float w = lrelu_exp(as_h[(size_t)d * 8] + adst_h);
        uint4 u = *reinterpret_cast<const uint4*>(hwl + ((size_t)d << 7));
        accu4(ac, w, u);
        dn = w;
    }

    // pipeline state: cB = cols for next group; lA/uA = data for current group
    int cB0 = 0, cB1 = 0, cB2 = 0, cB3 = 0;
    float lA0, lA1, lA2, lA3;
    uint4 uA0, uA1, uA2, uA3;
    if (e + 4 <= end) {
        int a0 = col[e], a1 = col[e + 1], a2 = col[e + 2], a3 = col[e + 3];
        if (e + 8 <= end) { cB0 = col[e + 4]; cB1 = col[e + 5]; cB2 = col[e + 6]; cB3 = col[e + 7]; }
        lA0 = as_h[(size_t)a0 * 8]; lA1 = as_h[(size_t)a1 * 8];
        lA2 = as_h[(size_t)a2 * 8]; lA3 = as_h[(size_t)a3 * 8];
        uA0 = *reinterpret_cast<const uint4*>(hwl + ((size_t)a0 << 7));
        uA1 = *reinterpret_cast<const uint4*>(hwl + ((size_t)a1 << 7));
        uA2 = *reinterpret_cast<const uint4*>(hwl + ((size_t)a2 << 7));
        uA3 = *reinterpret_cast<const uint4*>(hwl + ((size_t)a3 << 7));
    }
    while (e + 4 <= end) {
        int en = e + 4;
        bool hN = (en + 4 <= end);
        // cols for group k+2
        int cC0 = cB0, cC1 = cB1, cC2 = cB2, cC3 = cB3;
        if (en + 8 <= end) { cC0 = col[en + 4]; cC1 = col[en + 5]; cC2 = col[en + 6]; cC3 = col[en + 7]; }
        // data for group k+1 (issued now, consumed next iteration)
        float lB0, lB1, lB2, lB3;
        uint4 uB0, uB1, uB2, uB3;
        if (hN) {
            lB0 = as_h[(size_t)cB0 * 8]; lB1 = as_h[(size_t)cB1 * 8];
            lB2 = as_h[(size_t)cB2 * 8]; lB3 = as_h[(size_t)cB3 * 8];
            uB0 = *reinterpret_cast<const uint4*>(hwl + ((size_t)cB0 << 7));
            uB1 = *reinterpret_cast<const uint4*>(hwl + ((size_t)cB1 << 7));
            uB2 = *reinterpret_cast<const uint4*>(hwl + ((size_t)cB2 << 7));
            uB3 = *reinterpret_cast<const uint4*>(hwl + ((size_t)cB3 << 7));
        }
        // compute current group
        float w0 = lrelu_exp(lA0 + adst_h);
        float w1 = lrelu_exp(lA1 + adst_h);
        float w2 = lrelu_exp(lA2 + adst_h);
        float w3 = lrelu_exp(lA3 + adst_h);
        accu4(ac, w0, uA0); accu4(ac, w1, uA1);
        accu4(ac, w2, uA2); accu4(ac, w3, uA3);
        dn += w0 + w1 + w2 + w3;
        // rotate
        cB0 = cC0; cB1 = cC1; cB2 = cC2; cB3 = cC3;
        lA0 = lB0; lA1 = lB1; lA2 = lB2; lA3 = lB3;
        uA0 = uB0; uA1 = uB1; uA2 = uB2; uA3 = uB3;
        e = en;
    }
    for (; e < end; ++e) {
        int s = col[e];
        float w = lrelu_exp(as_h[(size_t)s * 8] + adst_h);
        uint4 u = *reinterpret_cast<const uint4*>(hwl + ((size_t)s << 7));
        accu4(ac, w, u);
        dn += w;
    }

    float rden = 1.f / (dn + 1e-16f);
    float o[8];
    float sm1 = 0.f, sm2 = 0.f;
    #pragma unroll
    for (int p = 0; p < 8; ++p) {
        o[p] = ac[p] * rden + bias[f0 + p];
        sm1 += o[p];
        sm2 += o[p] * o[p];
    }
    #pragma unroll
    for (int off = 8; off >= 1; off >>= 1) {
        sm1 += __shfl_xor(sm1, off, 16);
        sm2 += __shfl_xor(sm2, off, 16);
    }
    float mu = sm1 * (1.f / 128.f);
    float var = sm2 * (1.f / 128.f) - mu * mu;
    float inv = rsqrtf(var + 1e-5f);
    unsigned pk[4];
    #pragma unroll
    for (int p = 0; p < 8; p += 2) {
        float y0 = (o[p] - mu) * inv * g[f0 + p] + be[f0 + p];
        float y1 = (o[p + 1] - mu) * inv * g[f0 + p + 1] + be[f0 + p + 1];
        y0 = y0 > 0.f ? y0 : expm1f(y0);
        y1 = y1 > 0.f ? y1 : expm1f(y1);
        pk[p / 2] = (unsigned)f2bu(y0) | ((unsigned)f2bu(y1) << 16);
    }
    unsigned short* op = (unsigned short*)out + (size_t)d * 128 + f0;
    *reinterpret_cast<uint4*>(op) = make_uint4(pk[0], pk[1], pk[2], pk[3]);
}

// --- layer-2 agg + LN + ELU + fused gemm3 (64->10) + alpha3 -----------------
// LPD=8 (2 lanes per head), depth-1 pipelined; h3 slots 10..15 zero-filled.
__global__ __launch_bounds__(256) void agg_ln_l2_g3(
    const int2* __restrict__ ptrSE, const int* __restrict__ col,
    const float* __restrict__ asrc, const float* __restrict__ adst,
    const bf16* __restrict__ hb, const float* __restrict__ bias,
    const float* __restrict__ g, const float* __restrict__ be,
    const float* __restrict__ W3, const float* __restrict__ as3,
    const float* __restrict__ ad3,
    bf16* __restrict__ h3, float* __restrict__ asrc3, float* __restrict__ adst3,
    int N)
{
    __shared__ float Wl[640], s3[10], d3[10];
    int tid = threadIdx.x;
    for (int i = tid; i < 640; i += 256) Wl[i] = W3[i];
    if (tid < 10) { s3[tid] = as3[tid]; d3[tid] = ad3[tid]; }
    __syncthreads();
    int sub = tid >> 3, j = tid & 7;
    int d = blockIdx.x * 32 + sub;
    if (d >= N) return;
    int f0 = j * 8;
    int hd = j >> 1;                  // H=4: 2 lanes per head
    int2 se = ptrSE[d];
    int e = se.x, end = se.y;
    float adst_h = adst[d * 4 + hd];
    const unsigned short* hw = (const unsigned short*)hb;
    const unsigned short* hwl = hw + f0;
    const float* as_h = asrc + hd;

    float ac[8];
    #pragma unroll
    for (int p = 0; p < 8; ++p) ac[p] = 0.f;
    float dn;

    {   // self loop
        float w = lrelu_exp(as_h[(size_t)d * 4] + adst_h);
        uint4 u = *reinterpret_cast<const uint4*>(hwl + ((size_t)d << 6));
        accu4(ac, w, u);
        dn = w;
    }

    int cB0 = 0, cB1 = 0, cB2 = 0, cB3 = 0;
    float lA0, lA1, lA2, lA3;
    uint4 uA0, uA1, uA2, uA3;
    if (e + 4 <= end) {
        int a0 = col[e], a1 = col[e + 1], a2 = col[e + 2], a3 = col[e + 3];
        if (e + 8 <= end) { cB0 = col[e + 4]; cB1 = col[e + 5]; cB2 = col[e + 6]; cB3 = col[e + 7]; }
        lA0 = as_h[(size_t)a0 * 4]; lA1 = as_h[(size_t)a1 * 4];
        lA2 = as_h[(size_t)a2 * 4]; lA3 = as_h[(size_t)a3 * 4];
        uA0 = *reinterpret_cast<const uint4*>(hwl + ((size_t)a0 << 6));
        uA1 = *reinterpret_cast<const uint4*>(hwl + ((size_t)a1 << 6));
        uA2 = *reinterpret_cast<const uint4*>(hwl + ((size_t)a2 << 6));
        uA3 = *reinterpret_cast<const uint4*>(hwl + ((size_t)a3 << 6));
    }
    while (e + 4 <= end) {
        int en = e + 4;
        bool hN = (en + 4 <= end);
        int cC0 = cB0, cC1 = cB1, cC2 = cB2, cC3 = cB3;
        if (en + 8 <= end) { cC0 = col[en + 4]; cC1 = col[en + 5]; cC2 = col[en + 6]; cC3 = col[en + 7]; }
        float lB0, lB1, lB2, lB3;
        uint4 uB0, uB1, uB2, uB3;
        if (hN) {
            lB0 = as_h[(size_t)cB0 * 4]; lB1 = as_h[(size_t)cB1 * 4];
            lB2 = as_h[(size_t)cB2 * 4]; lB3 = as_h[(size_t)cB3 * 4];
            uB0 = *reinterpret_cast<const uint4*>(hwl + ((size_t)cB0 << 6));
            uB1 = *reinterpret_cast<const uint4*>(hwl + ((size_t)cB1 << 6));
            uB2 = *reinterpret_cast<const uint4*>(hwl + ((size_t)cB2 << 6));
            uB3 = *reinterpret_cast<const uint4*>(hwl + ((size_t)cB3 << 6));
        }
        float w0 = lrelu_exp(lA0 + adst_h);
        float w1 = lrelu_exp(lA1 + adst_h);
        float w2 = lrelu_exp(lA2 + adst_h);
        float w3 = lrelu_exp(lA3 + adst_h);
        accu4(ac, w0, uA0); accu4(ac, w1, uA1);
        accu4(ac, w2, uA2); accu4(ac, w3, uA3);
        dn += w0 + w1 + w2 + w3;
        cB0 = cC0; cB1 = cC1; cB2 = cC2; cB3 = cC3;
        lA0 = lB0; lA1 = lB1; lA2 = lB2; lA3 = lB3;
        uA0 = uB0; uA1 = uB1; uA2 = uB2; uA3 = uB3;
        e = en;
    }
    for (; e < end; ++e) {
        int s = col[e];
        float w = lrelu_exp(as_h[(size_t)s * 4] + adst_h);
        uint4 u = *reinterpret_cast<const uint4*>(hwl + ((size_t)s << 6));
        accu4(ac, w, u);
        dn += w;
    }

    float rden = 1.f / (dn + 1e-16f);
    float o[8];
    float sm1 = 0.f, sm2 = 0.f;
    #pragma unroll
    for (int p = 0; p < 8; ++p) {
        o[p] = ac[p] * rden + bias[f0 + p];
        sm1 += o[p];
        sm2 += o[p] * o[p];
    }
    #pragma unroll
    for (int off = 4; off >= 1; off >>= 1) {
        sm1 += __shfl_xor(sm1, off, 8);
        sm2 += __shfl_xor(sm2, off, 8);
    }
    float mu = sm1 * (1.f / 64.f);
    float var = sm2 * (1.f / 64.f) - mu * mu;
    float inv = rsqrtf(var + 1e-5f);
    float y[8];
    #pragma unroll
    for (int p = 0; p < 8; ++p) {
        float t = (o[p] - mu) * inv * g[f0 + p] + be[f0 + p];
        y[p] = t > 0.f ? t : expm1f(t);
    }
    // fused gemm3: partials over this lane's 8 features, butterfly over 8 lanes
    float pj[10];
    #pragma unroll
    for (int jj = 0; jj < 10; ++jj) {
        float s = 0.f;
        #pragma unroll
        for (int p = 0; p < 8; ++p)
            s += y[p] * Wl[(f0 + p) * 10 + jj];
        pj[jj] = s;
    }
    #pragma unroll
    for (int off = 4; off >= 1; off >>= 1)
        #pragma unroll
        for (int jj = 0; jj < 10; ++jj)
            pj[jj] += __shfl_xor(pj[jj], off, 8);
    if (j == 0) {
        unsigned short* hr = (unsigned short*)h3 + (size_t)d * 16;
        unsigned q0 = (unsigned)f2bu(pj[0]) | ((unsigned)f2bu(pj[1]) << 16);
        unsigned q1 = (unsigned)f2bu(pj[2]) | ((unsigned)f2bu(pj[3]) << 16);
        unsigned q2 = (unsigned)f2bu(pj[4]) | ((unsigned)f2bu(pj[5]) << 16);
        unsigned q3 = (unsigned)f2bu(pj[6]) | ((unsigned)f2bu(pj[7]) << 16);
        unsigned q4 = (unsigned)f2bu(pj[8]) | ((unsigned)f2bu(pj[9]) << 16);
        *reinterpret_cast<uint4*>(hr) = make_uint4(q0, q1, q2, q3);
        *reinterpret_cast<uint4*>(hr + 8) = make_uint4(q4, 0u, 0u, 0u);
        float a1 = 0.f, a2 = 0.f;
        #pragma unroll
        for (int jj = 0; jj < 10; ++jj) {
            a1 += pj[jj] * s3[jj];
            a2 += pj[jj] * d3[jj];
        }
        asrc3[d] = a1;
        adst3[d] = a2;
    }
}

// --- layer-3 agg + bias + log_softmax fused: 4-lane subgroup per dst --------
// h3 rows zero-padded to 16 -> no per-load masking; depth-1 pipeline.
__global__ __launch_bounds__(256) void agg_l3_final(
    const int2* __restrict__ ptrSE, const int* __restrict__ col,
    const float* __restrict__ asrc, const float* __restrict__ adst,
    const bf16* __restrict__ h, const float* __restrict__ b3,
    float* __restrict__ out, int N)
{
    int tid = threadIdx.x;
    int sub = tid >> 2, j = tid & 3;
    int d = blockIdx.x * 64 + sub;
    if (d >= N) return;
    const unsigned short* hu = (const unsigned short*)h;
    const unsigned short* hul = hu + j * 4;
    int2 se = ptrSE[d];
    int e = se.x, end = se.y;
    float adst_d = adst[d];

    float ac[4] = {0.f, 0.f, 0.f, 0.f};
    float dn;
    {   // self loop
        float w = lrelu_exp(asrc[d] + adst_d);
        uint2 u = *reinterpret_cast<const uint2*>(hul + (size_t)d * 16);
        accu2(ac, w, u);
        dn = w;
    }

    int cB0 = 0, cB1 = 0, cB2 = 0, cB3 = 0;
    float lA0, lA1, lA2, lA3;
    uint2 uA0, uA1, uA2, uA3;
    if (e + 4 <= end) {
        int a0 = col[e], a1 = col[e + 1], a2 = col[e + 2], a3 = col[e + 3];
        if (e + 8 <= end) { cB0 = col[e + 4]; cB1 = col[e + 5]; cB2 = col[e + 6]; cB3 = col[e + 7]; }
        lA0 = asrc[a0]; lA1 = asrc[a1]; lA2 = asrc[a2]; lA3 = asrc[a3];
        uA0 = *reinterpret_cast<const uint2*>(hul + (size_t)a0 * 16);
        uA1 = *reinterpret_cast<const uint2*>(hul + (size_t)a1 * 16);
        uA2 = *reinterpret_cast<const uint2*>(hul + (size_t)a2 * 16);
        uA3 = *reinterpret_cast<const uint2*>(hul + (size_t)a3 * 16);
    }
    while (e + 4 <= end) {
        int en = e + 4;
        bool hN = (en + 4 <= end);
        int cC0 = cB0, cC1 = cB1, cC2 = cB2, cC3 = cB3;
        if (en + 8 <= end) { cC0 = col[en + 4]; cC1 = col[en + 5]; cC2 = col[en + 6]; cC3 = col[en + 7]; }
        float lB0, lB1, lB2, lB3;
        uint2 uB0, uB1, uB2, uB3;
        if (hN) {
            lB0 = asrc[cB0]; lB1 = asrc[cB1]; lB2 = asrc[cB2]; lB3 = asrc[cB3];
            uB0 = *reinterpret_cast<const uint2*>(hul + (size_t)cB0 * 16);
            uB1 = *reinterpret_cast<const uint2*>(hul + (size_t)cB1 * 16);
            uB2 = *reinterpret_cast<const uint2*>(hul + (size_t)cB2 * 16);
            uB3 = *reinterpret_cast<const uint2*>(hul + (size_t)cB3 * 16);
        }
        float w0 = lrelu_exp(lA0 + adst_d);
        float w1 = lrelu_exp(lA1 + adst_d);
        float w2 = lrelu_exp(lA2 + adst_d);
        float w3 = lrelu_exp(lA3 + adst_d);
        accu2(ac, w0, uA0);
        accu2(ac, w1, uA1);
        accu2(ac, w2, uA2);
        accu2(ac, w3, uA3);
        dn += w0 + w1 + w2 + w3;
        cB0 = cC0; cB1 = cC1; cB2 = cC2; cB3 = cC3;
        lA0 = lB0; lA1 = lB1; lA2 = lB2; lA3 = lB3;
        uA0 = uB0; uA1 = uB1; uA2 = uB2; uA3 = uB3;
        e = en;
    }
    for (; e < end; ++e) {
        int s = col[e];
        float w = lrelu_exp(asrc[s] + adst_d);
        uint2 u = *reinterpret_cast<const uint2*>(hul + (size_t)s * 16);
        accu2(ac, w, u);
        dn += w;
    }

    float rden = 1.f / (dn + 1e-16f);
    int base = j * 4;
    float lv[4];
    #pragma unroll
    for (int p = 0; p < 4; ++p) {
        int idx = base + p;
        float bb = b3[idx < 10 ? idx : 9];
        lv[p] = (idx < 10) ? ac[p] * rden + bb : -1e30f;
    }
    float mx = fmaxf(fmaxf(lv[0], lv[1]), fmaxf(lv[2], lv[3]));
    mx = fmaxf(mx, __shfl_xor(mx, 1, 4));
    mx = fmaxf(mx, __shfl_xor(mx, 2, 4));
    float es = 0.f;
    #pragma unroll
    for (int p = 0; p < 4; ++p)
        es += __expf(lv[p] - mx);      // invalid lanes: exp(-1e30 - mx) == 0
    es += __shfl_xor(es, 1, 4);
    es += __shfl_xor(es, 2, 4);
    float ls = mx + logf(es);
    if (base < 10) {
        float* orow = out + (size_t)d * 10 + base;
        *reinterpret_cast<float2*>(orow) = make_float2(lv[0] - ls, lv[1] - ls);
        if (base + 2 < 10)
            *reinterpret_cast<float2*>(orow + 2) = make_float2(lv[2] - ls, lv[3] - ls);
    }
}

static inline int cdiv(long a, long b) { return (int)((a + b - 1) / b); }

extern "C" void kernel_launch(void* const* d_in, const int* in_sizes, int n_in,
                              void* d_out, int out_size, void* d_ws, size_t ws_size,
                              hipStream_t stream)
{
    const float* x   = (const float*)d_in[0];
    const int*   ei  = (const int*)d_in[1];
    const float* W1  = (const float*)d_in[2];
    const float* as1 = (const float*)d_in[3];
    const float* ad1 = (const float*)d_in[4];
    const float* b1  = (const float*)d_in[5];
    const float* g1  = (const float*)d_in[6];
    const float* be1 = (const float*)d_in[7];
    const float* W2  = (const float*)d_in[8];
    const float* as2 = (const float*)d_in[9];
    const float* ad2 = (const float*)d_in[10];
    const float* b2  = (const float*)d_in[11];
    const float* g2  = (const float*)d_in[12];
    const float* be2 = (const float*)d_in[13];
    const float* W3  = (const float*)d_in[14];
    const float* as3 = (const float*)d_in[15];
    const float* ad3 = (const float*)d_in[16];
    const float* b3  = (const float*)d_in[17];

    const int N = in_sizes[0] / 128;
    const int E = in_sizes[1] / 2;

    const int NBLK = cdiv(E, CSR_CH);
    const int NCH  = cdiv(N, 256);

    bf16*     hb    = (bf16*)d_ws;                      // N*128 bf16 (gather table)
    bf16*     aggb  = hb + (size_t)N * 128;             // N*128 bf16 (LN out L1 / h3 L3)
    float*    asrc  = (float*)(aggb + (size_t)N * 128); // N*8
    float*    adst  = asrc + (size_t)N * 8;             // N*8
    float*    asrc3 = adst + (size_t)N * 8;             // N
    float*    adst3 = asrc3 + N;                        // N
    int*      col   = (int*)(adst3 + N);                // E
    int2*     ptrSE = (int2*)(col + E);                 // N
    int*      cnt   = (int*)(ptrSE + N);                // N
    int*      off   = cnt + N;                          // N
    int*      bsum  = off + N;                          // NCH
    int*      boff  = bsum + NCH;                       // NCH
    bf16*     h3b   = aggb;                             // N*16 bf16 (layer 3 logits)

    const int NG1 = cdiv(N, 64);

    // zero per-dst counts, then layer-1 GEMM (+alpha) fused with hist blocks
    hipMemsetAsync(cnt, 0, (size_t)N * sizeof(int), stream);
    gemm_mfma<float, 8><<<NG1 + NBLK, 256, 0, stream>>>(
        x, W1, as1, ad1, hb, asrc, adst, N, NG1, ei, E, cnt);
    // direct CSR build: scan counts -> offsets, then single-pass scatter
    csr_scanA<<<NCH, 256, 0, stream>>>(cnt, N, bsum);
    csr_scanB<<<1, 512, 0, stream>>>(bsum, NCH, boff);
    csr_scanC<<<NCH, 256, 0, stream>>>(cnt, boff, N, off, ptrSE);
    csr_scatter<<<1024, 256, 0, stream>>>(ei, E, off, col);

    // layer 1 aggregation -> LN -> ELU (bf16 out in aggb)
    agg_ln_l1<<<cdiv(N, 16), 256, 0, stream>>>(
        ptrSE, col, asrc, adst, hb, b1, g1, be1, aggb, N);

    // layer 2 GEMM (+alpha), no hist blocks
    const int NG2 = cdiv(N, 64);
    gemm_mfma<bf16, 4><<<NG2, 256, 0, stream>>>(
        aggb, W2, as2, ad2, hb, asrc, adst, N, NG2, nullptr, 0, nullptr);

    // layer 2 aggregation -> LN -> ELU -> fused gemm3 + alpha3 (h3 into aggb)
    agg_ln_l2_g3<<<cdiv(N, 32), 256, 0, stream>>>(
        ptrSE, col, asrc, adst, hb, b2, g2, be2, W3, as3, ad3,
        h3b, asrc3, adst3, N);

    // layer 3 aggregation + bias + log_softmax -> d_out
    agg_l3_final<<<cdiv(N, 64), 256, 0, stream>>>(
        ptrSE, col, asrc3, adst3, h3b, b3, (float*)d_out, N);
}

// Round 6
// 344.661 us; speedup vs baseline: 1.4791x; 1.4791x over previous
//
#include <hip/hip_runtime.h>
#include <hip/hip_bf16.h>
#include <math.h>

typedef __hip_bfloat16 bf16;
typedef __bf16 bf16x8 __attribute__((ext_vector_type(8)));
typedef float floatx4 __attribute__((ext_vector_type(4)));

#define CSR_CH  4096
#define CSR_REG 8192

__device__ __forceinline__ unsigned short f2bu(float f) {
    bf16 b = __float2bfloat16(f);
    return __builtin_bit_cast(unsigned short, b);
}
__device__ __forceinline__ float bu2f(unsigned short u) {
    return __uint_as_float(((unsigned)u) << 16);
}

// accumulate 8 bf16 (packed in uint4) scaled by w into ac[0..7]
__device__ __forceinline__ void accu4(float* ac, float w, uint4 u) {
    ac[0] += w * __uint_as_float(u.x << 16);
    ac[1] += w * __uint_as_float(u.x & 0xffff0000u);
    ac[2] += w * __uint_as_float(u.y << 16);
    ac[3] += w * __uint_as_float(u.y & 0xffff0000u);
    ac[4] += w * __uint_as_float(u.z << 16);
    ac[5] += w * __uint_as_float(u.z & 0xffff0000u);
    ac[6] += w * __uint_as_float(u.w << 16);
    ac[7] += w * __uint_as_float(u.w & 0xffff0000u);
}
// accumulate 4 bf16 (packed in uint2) scaled by w into ac[0..3]
__device__ __forceinline__ void accu2(float* ac, float w, uint2 u) {
    ac[0] += w * __uint_as_float(u.x << 16);
    ac[1] += w * __uint_as_float(u.x & 0xffff0000u);
    ac[2] += w * __uint_as_float(u.y << 16);
    ac[3] += w * __uint_as_float(u.y & 0xffff0000u);
}

__device__ __forceinline__ float lrelu_exp(float lg) {
    lg = lg > 0.f ? lg : 0.2f * lg;
    return __expf(lg);
}

// ====== MFMA GEMM + fused alpha (+ optional csr_hist blocks) ================
// blocks [0,NG): GEMM; blocks [NG, NG+NBLK): csr_hist (aliases Wt LDS).
template<typename XT, int H>
__global__ __launch_bounds__(256) void gemm_mfma(
    const XT* __restrict__ X, const float* __restrict__ W,
    const float* __restrict__ a_src, const float* __restrict__ a_dst,
    bf16* __restrict__ Hout, float* __restrict__ asrc, float* __restrict__ adst,
    int N, int NG, const int* __restrict__ ei, int E, int DPB,
    int* __restrict__ histM)
{
    constexpr int M = H * 16;
    constexpr int KP = 136;
    constexpr int NT = M / 16;
    constexpr int HPQ = H / 4;
    __shared__ __align__(16) unsigned short Wt[M * KP];
    __shared__ __align__(16) unsigned short As[64 * KP];
    __shared__ float As_s[M], Ad_s[M];
    int tid = threadIdx.x;

    if (blockIdx.x >= NG) {          // ---- csr_hist path ----
        int* cnt = (int*)Wt;
        cnt[tid] = 0;
        __syncthreads();
        int blk = blockIdx.x - NG;
        int e0 = blk * CSR_CH;
        int e1 = min(E, e0 + CSR_CH);
        for (int e = e0 + tid; e < e1; e += 256)
            atomicAdd(&cnt[ei[E + e] / DPB], 1);
        __syncthreads();
        histM[blk * 256 + tid] = cnt[tid];
        return;
    }

    int r0 = blockIdx.x * 64;
    for (int i = tid; i < M; i += 256) { As_s[i] = a_src[i]; Ad_s[i] = a_dst[i]; }
    for (int idx = tid; idx < 128 * M; idx += 256) {
        int k = idx / M, m = idx % M;
        Wt[m * KP + k] = f2bu(W[idx]);
    }
    if constexpr (__is_same(XT, float)) {
        for (int idx = tid; idx < 64 * 32; idx += 256) {
            int row = idx >> 5, c4 = (idx & 31) * 4;
            int grow = r0 + row;
            float4 v = make_float4(0.f, 0.f, 0.f, 0.f);
            if (grow < N)
                v = *reinterpret_cast<const float4*>(X + (size_t)grow * 128 + c4);
            unsigned short* a = &As[row * KP + c4];
            a[0] = f2bu(v.x); a[1] = f2bu(v.y); a[2] = f2bu(v.z); a[3] = f2bu(v.w);
        }
    } else {
        for (int idx = tid; idx < 64 * 16; idx += 256) {
            int row = idx >> 4, c8 = (idx & 15) * 8;
            int grow = r0 + row;
            uint4 v = make_uint4(0u, 0u, 0u, 0u);
            if (grow < N)
                v = *reinterpret_cast<const uint4*>((const unsigned short*)X + (size_t)grow * 128 + c8);
            *reinterpret_cast<uint4*>(&As[row * KP + c8]) = v;
        }
    }
    __syncthreads();

    int w = tid >> 6, l = tid & 63, q = l >> 4, c = l & 15;
    floatx4 acc[NT];
    #pragma unroll
    for (int t = 0; t < NT; ++t) acc[t] = (floatx4){0.f, 0.f, 0.f, 0.f};

    #pragma unroll
    for (int kc = 0; kc < 4; ++kc) {
        bf16x8 a = *reinterpret_cast<const bf16x8*>(&As[(w * 16 + c) * KP + kc * 32 + q * 8]);
        #pragma unroll
        for (int t = 0; t < NT; ++t) {
            bf16x8 b = *reinterpret_cast<const bf16x8*>(&Wt[(t * 16 + c) * KP + kc * 32 + q * 8]);
            acc[t] = __builtin_amdgcn_mfma_f32_16x16x32_bf16(a, b, acc[t], 0, 0, 0);
        }
    }
    __syncthreads();
    #pragma unroll
    for (int t = 0; t < NT; ++t)
        #pragma unroll
        for (int r = 0; r < 4; ++r)
            As[(w * 16 + q * 4 + r) * KP + t * 16 + c] = f2bu(acc[t][r]);
    __syncthreads();
    for (int idx = tid; idx < 64 * (M / 8); idx += 256) {
        int row = idx / (M / 8), g = idx % (M / 8);
        int grow = r0 + row;
        if (grow < N)
            *reinterpret_cast<uint4*>(Hout + (size_t)grow * M + g * 8) =
                *reinterpret_cast<const uint4*>(&As[row * KP + g * 8]);
    }
    {
        int r = tid >> 2, qq = tid & 3;
        int grow = r0 + r;
        if (grow < N) {
            #pragma unroll
            for (int hh = 0; hh < HPQ; ++hh) {
                int hd = qq * HPQ + hh;
                float s1 = 0.f, s2 = 0.f;
                #pragma unroll
                for (int f = 0; f < 16; f += 2) {
                    unsigned u = *reinterpret_cast<const unsigned*>(&As[r * KP + hd * 16 + f]);
                    float v0 = __uint_as_float(u << 16);
                    float v1 = __uint_as_float(u & 0xffff0000u);
                    s1 += v0 * As_s[hd * 16 + f] + v1 * As_s[hd * 16 + f + 1];
                    s2 += v0 * Ad_s[hd * 16 + f] + v1 * Ad_s[hd * 16 + f + 1];
                }
                asrc[(size_t)grow * H + hd] = s1;
                adst[(size_t)grow * H + hd] = s2;
            }
        }
    }
}

// ============== atomic-free CSR build (hist fused into gemm1) ================
__global__ __launch_bounds__(256) void csr_colscan(
    const int* __restrict__ histM, int NBLK,
    int* __restrict__ offT, int* __restrict__ btot)
{
    __shared__ int sm[512];
    int b = blockIdx.x;
    int tid = threadIdx.x;
    int i0 = tid, i1 = tid + 256;
    sm[i0] = (i0 < NBLK) ? histM[i0 * 256 + b] : 0;
    sm[i1] = (i1 < NBLK) ? histM[i1 * 256 + b] : 0;
    __syncthreads();
    #pragma unroll
    for (int o = 1; o < 512; o <<= 1) {
        int t0 = (i0 >= o) ? sm[i0 - o] : 0;
        int t1 = (i1 >= o) ? sm[i1 - o] : 0;
        __syncthreads();
        sm[i0] += t0; sm[i1] += t1;
        __syncthreads();
    }
    if (i0 < NBLK) offT[b * NBLK + i0] = b * CSR_REG + ((i0 == 0) ? 0 : sm[i0 - 1]);
    if (i1 < NBLK) offT[b * NBLK + i1] = b * CSR_REG + sm[i1 - 1];
    if (tid == 0) btot[b] = sm[511];
}

__global__ __launch_bounds__(512) void csr_pair_scatter(
    const int* __restrict__ ei, int E, int DPB,
    const int* __restrict__ offT, int NBLK,
    unsigned* __restrict__ pairs)
{
    __shared__ int cnt[256];
    int tid = threadIdx.x;
    int blk = blockIdx.x;
    if (tid < 256) cnt[tid] = offT[tid * NBLK + blk];
    __syncthreads();
    int e0 = blk * CSR_CH;
    int e1 = min(E, e0 + CSR_CH);
    for (int e = e0 + tid; e < e1; e += 512) {
        int s = ei[e];
        int d = ei[E + e];
        int b = d / DPB;
        int dloc = d - b * DPB;
        int pos = atomicAdd(&cnt[b], 1);
        pairs[pos] = ((unsigned)dloc << 17) | (unsigned)s;
    }
}

__global__ __launch_bounds__(512) void csr_fine(
    const unsigned* __restrict__ pairs, const int* __restrict__ btot,
    int DPB, int N, int2* __restrict__ ptrSE, int* __restrict__ col)
{
    __shared__ int sm[512];
    __shared__ int off[512];
    int b = blockIdx.x;
    int tid = threadIdx.x;
    int base = b * CSR_REG;
    int tot = btot[b];
    int d0 = b * DPB;
    sm[tid] = 0;
    __syncthreads();
    for (int i = tid; i < tot; i += 512)
        atomicAdd(&sm[pairs[base + i] >> 17], 1);
    __syncthreads();
    #pragma unroll
    for (int o = 1; o < 512; o <<= 1) {
        int t = (tid >= o) ? sm[tid - o] : 0;
        __syncthreads();
        sm[tid] += t;
        __syncthreads();
    }
    int s_e = base + ((tid == 0) ? 0 : sm[tid - 1]);
    int e_e = base + sm[tid];
    off[tid] = s_e;
    if (tid < DPB && d0 + tid < N) ptrSE[d0 + tid] = make_int2(s_e, e_e);
    __syncthreads();
    for (int i = tid; i < tot; i += 512) {
        unsigned p = pairs[base + i];
        int pos = atomicAdd(&off[p >> 17], 1);
        col[pos] = (int)(p & 0x1FFFFu);
    }
}

// ------- layer-1 CSR agg + bias + LN + ELU: 16-lane subgroup per dst --------
// Depth-1 pipeline: cols fetched 2 groups ahead, asrc+row data 1 group ahead.
__global__ __launch_bounds__(256) void agg_ln_l1(
    const int2* __restrict__ ptrSE, const int* __restrict__ col,
    const float* __restrict__ asrc, const float* __restrict__ adst,
    const bf16* __restrict__ hb, const float* __restrict__ bias,
    const float* __restrict__ g, const float* __restrict__ be,
    bf16* __restrict__ out, int N)
{
    int tid = threadIdx.x;
    int sub = tid >> 4, j = tid & 15;
    int d = blockIdx.x * 16 + sub;
    if (d >= N) return;
    int f0 = j * 8;
    int hd = j >> 1;                  // H=8: 2 lanes per head
    int2 se = ptrSE[d];
    int e = se.x, end = se.y;
    float adst_h = adst[d * 8 + hd];
    const unsigned short* hw = (const unsigned short*)hb;
    const unsigned short* hwl = hw + f0;
    const float* as_h = asrc + hd;

    float ac[8];
    #pragma unroll
    for (int p = 0; p < 8; ++p) ac[p] = 0.f;
    float dn;

    {   // self loop
        float w = lrelu_exp(as_h[(size_t)d * 8] + adst_h);
        uint4 u = *reinterpret_cast<const uint4*>(hwl + ((size_t)d << 7));
        accu4(ac, w, u);
        dn = w;
    }

    // pipeline state: cB = cols for next group; lA/uA = data for current group
    int cB0 = 0, cB1 = 0, cB2 = 0, cB3 = 0;
    float lA0, lA1, lA2, lA3;
    uint4 uA0, uA1, uA2, uA3;
    if (e + 4 <= end) {
        int a0 = col[e], a1 = col[e + 1], a2 = col[e + 2], a3 = col[e + 3];
        if (e + 8 <= end) { cB0 = col[e + 4]; cB1 = col[e + 5]; cB2 = col[e + 6]; cB3 = col[e + 7]; }
        lA0 = as_h[(size_t)a0 * 8]; lA1 = as_h[(size_t)a1 * 8];
        lA2 = as_h[(size_t)a2 * 8]; lA3 = as_h[(size_t)a3 * 8];
        uA0 = *reinterpret_cast<const uint4*>(hwl + ((size_t)a0 << 7));
        uA1 = *reinterpret_cast<const uint4*>(hwl + ((size_t)a1 << 7));
        uA2 = *reinterpret_cast<const uint4*>(hwl + ((size_t)a2 << 7));
        uA3 = *reinterpret_cast<const uint4*>(hwl + ((size_t)a3 << 7));
    }
    while (e + 4 <= end) {
        int en = e + 4;
        bool hN = (en + 4 <= end);
        // cols for group k+2
        int cC0 = cB0, cC1 = cB1, cC2 = cB2, cC3 = cB3;
        if (en + 8 <= end) { cC0 = col[en + 4]; cC1 = col[en + 5]; cC2 = col[en + 6]; cC3 = col[en + 7]; }
        // data for group k+1 (issued now, consumed next iteration)
        float lB0, lB1, lB2, lB3;
        uint4 uB0, uB1, uB2, uB3;
        if (hN) {
            lB0 = as_h[(size_t)cB0 * 8]; lB1 = as_h[(size_t)cB1 * 8];
            lB2 = as_h[(size_t)cB2 * 8]; lB3 = as_h[(size_t)cB3 * 8];
            uB0 = *reinterpret_cast<const uint4*>(hwl + ((size_t)cB0 << 7));
            uB1 = *reinterpret_cast<const uint4*>(hwl + ((size_t)cB1 << 7));
            uB2 = *reinterpret_cast<const uint4*>(hwl + ((size_t)cB2 << 7));
            uB3 = *reinterpret_cast<const uint4*>(hwl + ((size_t)cB3 << 7));
        }
        // compute current group
        float w0 = lrelu_exp(lA0 + adst_h);
        float w1 = lrelu_exp(lA1 + adst_h);
        float w2 = lrelu_exp(lA2 + adst_h);
        float w3 = lrelu_exp(lA3 + adst_h);
        accu4(ac, w0, uA0); accu4(ac, w1, uA1);
        accu4(ac, w2, uA2); accu4(ac, w3, uA3);
        dn += w0 + w1 + w2 + w3;
        // rotate
        cB0 = cC0; cB1 = cC1; cB2 = cC2; cB3 = cC3;
        lA0 = lB0; lA1 = lB1; lA2 = lB2; lA3 = lB3;
        uA0 = uB0; uA1 = uB1; uA2 = uB2; uA3 = uB3;
        e = en;
    }
    for (; e < end; ++e) {
        int s = col[e];
        float w = lrelu_exp(as_h[(size_t)s * 8] + adst_h);
        uint4 u = *reinterpret_cast<const uint4*>(hwl + ((size_t)s << 7));
        accu4(ac, w, u);
        dn += w;
    }

    float rden = 1.f / (dn + 1e-16f);
    float o[8];
    float sm1 = 0.f, sm2 = 0.f;
    #pragma unroll
    for (int p = 0; p < 8; ++p) {
        o[p] = ac[p] * rden + bias[f0 + p];
        sm1 += o[p];
        sm2 += o[p] * o[p];
    }
    #pragma unroll
    for (int off = 8; off >= 1; off >>= 1) {
        sm1 += __shfl_xor(sm1, off, 16);
        sm2 += __shfl_xor(sm2, off, 16);
    }
    float mu = sm1 * (1.f / 128.f);
    float var = sm2 * (1.f / 128.f) - mu * mu;
    float inv = rsqrtf(var + 1e-5f);
    unsigned pk[4];
    #pragma unroll
    for (int p = 0; p < 8; p += 2) {
        float y0 = (o[p] - mu) * inv * g[f0 + p] + be[f0 + p];
        float y1 = (o[p + 1] - mu) * inv * g[f0 + p + 1] + be[f0 + p + 1];
        y0 = y0 > 0.f ? y0 : expm1f(y0);
        y1 = y1 > 0.f ? y1 : expm1f(y1);
        pk[p / 2] = (unsigned)f2bu(y0) | ((unsigned)f2bu(y1) << 16);
    }
    unsigned short* op = (unsigned short*)out + (size_t)d * 128 + f0;
    *reinterpret_cast<uint4*>(op) = make_uint4(pk[0], pk[1], pk[2], pk[3]);
}

// --- layer-2 agg + LN + ELU + fused gemm3 (64->10) + alpha3 -----------------
// LPD=8 (2 lanes per head), depth-1 pipelined; h3 slots 10..15 zero-filled.
__global__ __launch_bounds__(256) void agg_ln_l2_g3(
    const int2* __restrict__ ptrSE, const int* __restrict__ col,
    const float* __restrict__ asrc, const float* __restrict__ adst,
    const bf16* __restrict__ hb, const float* __restrict__ bias,
    const float* __restrict__ g, const float* __restrict__ be,
    const float* __restrict__ W3, const float* __restrict__ as3,
    const float* __restrict__ ad3,
    bf16* __restrict__ h3, float* __restrict__ asrc3, float* __restrict__ adst3,
    int N)
{
    __shared__ float Wl[640], s3[10], d3[10];
    int tid = threadIdx.x;
    for (int i = tid; i < 640; i += 256) Wl[i] = W3[i];
    if (tid < 10) { s3[tid] = as3[tid]; d3[tid] = ad3[tid]; }
    __syncthreads();
    int sub = tid >> 3, j = tid & 7;
    int d = blockIdx.x * 32 + sub;
    if (d >= N) return;
    int f0 = j * 8;
    int hd = j >> 1;                  // H=4: 2 lanes per head
    int2 se = ptrSE[d];
    int e = se.x, end = se.y;
    float adst_h = adst[d * 4 + hd];
    const unsigned short* hw = (const unsigned short*)hb;
    const unsigned short* hwl = hw + f0;
    const float* as_h = asrc + hd;

    float ac[8];
    #pragma unroll
    for (int p = 0; p < 8; ++p) ac[p] = 0.f;
    float dn;

    {   // self loop
        float w = lrelu_exp(as_h[(size_t)d * 4] + adst_h);
        uint4 u = *reinterpret_cast<const uint4*>(hwl + ((size_t)d << 6));
        accu4(ac, w, u);
        dn = w;
    }

    int cB0 = 0, cB1 = 0, cB2 = 0, cB3 = 0;
    float lA0, lA1, lA2, lA3;
    uint4 uA0, uA1, uA2, uA3;
    if (e + 4 <= end) {
        int a0 = col[e], a1 = col[e + 1], a2 = col[e + 2], a3 = col[e + 3];
        if (e + 8 <= end) { cB0 = col[e + 4]; cB1 = col[e + 5]; cB2 = col[e + 6]; cB3 = col[e + 7]; }
        lA0 = as_h[(size_t)a0 * 4]; lA1 = as_h[(size_t)a1 * 4];
        lA2 = as_h[(size_t)a2 * 4]; lA3 = as_h[(size_t)a3 * 4];
        uA0 = *reinterpret_cast<const uint4*>(hwl + ((size_t)a0 << 6));
        uA1 = *reinterpret_cast<const uint4*>(hwl + ((size_t)a1 << 6));
        uA2 = *reinterpret_cast<const uint4*>(hwl + ((size_t)a2 << 6));
        uA3 = *reinterpret_cast<const uint4*>(hwl + ((size_t)a3 << 6));
    }
    while (e + 4 <= end) {
        int en = e + 4;
        bool hN = (en + 4 <= end);
        int cC0 = cB0, cC1 = cB1, cC2 = cB2, cC3 = cB3;
        if (en + 8 <= end) { cC0 = col[en + 4]; cC1 = col[en + 5]; cC2 = col[en + 6]; cC3 = col[en + 7]; }
        float lB0, lB1, lB2, lB3;
        uint4 uB0, uB1, uB2, uB3;
        if (hN) {
            lB0 = as_h[(size_t)cB0 * 4]; lB1 = as_h[(size_t)cB1 * 4];
            lB2 = as_h[(size_t)cB2 * 4]; lB3 = as_h[(size_t)cB3 * 4];
            uB0 = *reinterpret_cast<const uint4*>(hwl + ((size_t)cB0 << 6));
            uB1 = *reinterpret_cast<const uint4*>(hwl + ((size_t)cB1 << 6));
            uB2 = *reinterpret_cast<const uint4*>(hwl + ((size_t)cB2 << 6));
            uB3 = *reinterpret_cast<const uint4*>(hwl + ((size_t)cB3 << 6));
        }
        float w0 = lrelu_exp(lA0 + adst_h);
        float w1 = lrelu_exp(lA1 + adst_h);
        float w2 = lrelu_exp(lA2 + adst_h);
        float w3 = lrelu_exp(lA3 + adst_h);
        accu4(ac, w0, uA0); accu4(ac, w1, uA1);
        accu4(ac, w2, uA2); accu4(ac, w3, uA3);
        dn += w0 + w1 + w2 + w3;
        cB0 = cC0; cB1 = cC1; cB2 = cC2; cB3 = cC3;
        lA0 = lB0; lA1 = lB1; lA2 = lB2; lA3 = lB3;
        uA0 = uB0; uA1 = uB1; uA2 = uB2; uA3 = uB3;
        e = en;
    }
    for (; e < end; ++e) {
        int s = col[e];
        float w = lrelu_exp(as_h[(size_t)s * 4] + adst_h);
        uint4 u = *reinterpret_cast<const uint4*>(hwl + ((size_t)s << 6));
        accu4(ac, w, u);
        dn += w;
    }

    float rden = 1.f / (dn + 1e-16f);
    float o[8];
    float sm1 = 0.f, sm2 = 0.f;
    #pragma unroll
    for (int p = 0; p < 8; ++p) {
        o[p] = ac[p] * rden + bias[f0 + p];
        sm1 += o[p];
        sm2 += o[p] * o[p];
    }
    #pragma unroll
    for (int off = 4; off >= 1; off >>= 1) {
        sm1 += __shfl_xor(sm1, off, 8);
        sm2 += __shfl_xor(sm2, off, 8);
    }
    float mu = sm1 * (1.f / 64.f);
    float var = sm2 * (1.f / 64.f) - mu * mu;
    float inv = rsqrtf(var + 1e-5f);
    float y[8];
    #pragma unroll
    for (int p = 0; p < 8; ++p) {
        float t = (o[p] - mu) * inv * g[f0 + p] + be[f0 + p];
        y[p] = t > 0.f ? t : expm1f(t);
    }
    // fused gemm3: partials over this lane's 8 features, butterfly over 8 lanes
    float pj[10];
    #pragma unroll
    for (int jj = 0; jj < 10; ++jj) {
        float s = 0.f;
        #pragma unroll
        for (int p = 0; p < 8; ++p)
            s += y[p] * Wl[(f0 + p) * 10 + jj];
        pj[jj] = s;
    }
    #pragma unroll
    for (int off = 4; off >= 1; off >>= 1)
        #pragma unroll
        for (int jj = 0; jj < 10; ++jj)
            pj[jj] += __shfl_xor(pj[jj], off, 8);
    if (j == 0) {
        unsigned short* hr = (unsigned short*)h3 + (size_t)d * 16;
        unsigned q0 = (unsigned)f2bu(pj[0]) | ((unsigned)f2bu(pj[1]) << 16);
        unsigned q1 = (unsigned)f2bu(pj[2]) | ((unsigned)f2bu(pj[3]) << 16);
        unsigned q2 = (unsigned)f2bu(pj[4]) | ((unsigned)f2bu(pj[5]) << 16);
        unsigned q3 = (unsigned)f2bu(pj[6]) | ((unsigned)f2bu(pj[7]) << 16);
        unsigned q4 = (unsigned)f2bu(pj[8]) | ((unsigned)f2bu(pj[9]) << 16);
        *reinterpret_cast<uint4*>(hr) = make_uint4(q0, q1, q2, q3);
        *reinterpret_cast<uint4*>(hr + 8) = make_uint4(q4, 0u, 0u, 0u);
        float a1 = 0.f, a2 = 0.f;
        #pragma unroll
        for (int jj = 0; jj < 10; ++jj) {
            a1 += pj[jj] * s3[jj];
            a2 += pj[jj] * d3[jj];
        }
        asrc3[d] = a1;
        adst3[d] = a2;
    }
}

// --- layer-3 agg + bias + log_softmax fused: 4-lane subgroup per dst --------
// h3 rows zero-padded to 16 -> no per-load masking; depth-1 pipeline.
__global__ __launch_bounds__(256) void agg_l3_final(
    const int2* __restrict__ ptrSE, const int* __restrict__ col,
    const float* __restrict__ asrc, const float* __restrict__ adst,
    const bf16* __restrict__ h, const float* __restrict__ b3,
    float* __restrict__ out, int N)
{
    int tid = threadIdx.x;
    int sub = tid >> 2, j = tid & 3;
    int d = blockIdx.x * 64 + sub;
    if (d >= N) return;
    const unsigned short* hu = (const unsigned short*)h;
    const unsigned short* hul = hu + j * 4;
    int2 se = ptrSE[d];
    int e = se.x, end = se.y;
    float adst_d = adst[d];

    float ac[4] = {0.f, 0.f, 0.f, 0.f};
    float dn;
    {   // self loop
        float w = lrelu_exp(asrc[d] + adst_d);
        uint2 u = *reinterpret_cast<const uint2*>(hul + (size_t)d * 16);
        accu2(ac, w, u);
        dn = w;
    }

    int cB0 = 0, cB1 = 0, cB2 = 0, cB3 = 0;
    float lA0, lA1, lA2, lA3;
    uint2 uA0, uA1, uA2, uA3;
    if (e + 4 <= end) {
        int a0 = col[e], a1 = col[e + 1], a2 = col[e + 2], a3 = col[e + 3];
        if (e + 8 <= end) { cB0 = col[e + 4]; cB1 = col[e + 5]; cB2 = col[e + 6]; cB3 = col[e + 7]; }
        lA0 = asrc[a0]; lA1 = asrc[a1]; lA2 = asrc[a2]; lA3 = asrc[a3];
        uA0 = *reinterpret_cast<const uint2*>(hul + (size_t)a0 * 16);
        uA1 = *reinterpret_cast<const uint2*>(hul + (size_t)a1 * 16);
        uA2 = *reinterpret_cast<const uint2*>(hul + (size_t)a2 * 16);
        uA3 = *reinterpret_cast<const uint2*>(hul + (size_t)a3 * 16);
    }
    while (e + 4 <= end) {
        int en = e + 4;
        bool hN = (en + 4 <= end);
        int cC0 = cB0, cC1 = cB1, cC2 = cB2, cC3 = cB3;
        if (en + 8 <= end) { cC0 = col[en + 4]; cC1 = col[en + 5]; cC2 = col[en + 6]; cC3 = col[en + 7]; }
        float lB0, lB1, lB2, lB3;
        uint2 uB0, uB1, uB2, uB3;
        if (hN) {
            lB0 = asrc[cB0]; lB1 = asrc[cB1]; lB2 = asrc[cB2]; lB3 = asrc[cB3];
            uB0 = *reinterpret_cast<const uint2*>(hul + (size_t)cB0 * 16);
            uB1 = *reinterpret_cast<const uint2*>(hul + (size_t)cB1 * 16);
            uB2 = *reinterpret_cast<const uint2*>(hul + (size_t)cB2 * 16);
            uB3 = *reinterpret_cast<const uint2*>(hul + (size_t)cB3 * 16);
        }
        float w0 = lrelu_exp(lA0 + adst_d);
        float w1 = lrelu_exp(lA1 + adst_d);
        float w2 = lrelu_exp(lA2 + adst_d);
        float w3 = lrelu_exp(lA3 + adst_d);
        accu2(ac, w0, uA0);
        accu2(ac, w1, uA1);
        accu2(ac, w2, uA2);
        accu2(ac, w3, uA3);
        dn += w0 + w1 + w2 + w3;
        cB0 = cC0; cB1 = cC1; cB2 = cC2; cB3 = cC3;
        lA0 = lB0; lA1 = lB1; lA2 = lB2; lA3 = lB3;
        uA0 = uB0; uA1 = uB1; uA2 = uB2; uA3 = uB3;
        e = en;
    }
    for (; e < end; ++e) {
        int s = col[e];
        float w = lrelu_exp(asrc[s] + adst_d);
        uint2 u = *reinterpret_cast<const uint2*>(hul + (size_t)s * 16);
        accu2(ac, w, u);
        dn += w;
    }

    float rden = 1.f / (dn + 1e-16f);
    int base = j * 4;
    float lv[4];
    #pragma unroll
    for (int p = 0; p < 4; ++p) {
        int idx = base + p;
        float bb = b3[idx < 10 ? idx : 9];
        lv[p] = (idx < 10) ? ac[p] * rden + bb : -1e30f;
    }
    float mx = fmaxf(fmaxf(lv[0], lv[1]), fmaxf(lv[2], lv[3]));
    mx = fmaxf(mx, __shfl_xor(mx, 1, 4));
    mx = fmaxf(mx, __shfl_xor(mx, 2, 4));
    float es = 0.f;
    #pragma unroll
    for (int p = 0; p < 4; ++p)
        es += __expf(lv[p] - mx);      // invalid lanes: exp(-1e30 - mx) == 0
    es += __shfl_xor(es, 1, 4);
    es += __shfl_xor(es, 2, 4);
    float ls = mx + logf(es);
    if (base < 10) {
        float* orow = out + (size_t)d * 10 + base;
        *reinterpret_cast<float2*>(orow) = make_float2(lv[0] - ls, lv[1] - ls);
        if (base + 2 < 10)
            *reinterpret_cast<float2*>(orow + 2) = make_float2(lv[2] - ls, lv[3] - ls);
    }
}

static inline int cdiv(long a, long b) { return (int)((a + b - 1) / b); }

extern "C" void kernel_launch(void* const* d_in, const int* in_sizes, int n_in,
                              void* d_out, int out_size, void* d_ws, size_t ws_size,
                              hipStream_t stream)
{
    const float* x   = (const float*)d_in[0];
    const int*   ei  = (const int*)d_in[1];
    const float* W1  = (const float*)d_in[2];
    const float* as1 = (const float*)d_in[3];
    const float* ad1 = (const float*)d_in[4];
    const float* b1  = (const float*)d_in[5];
    const float* g1  = (const float*)d_in[6];
    const float* be1 = (const float*)d_in[7];
    const float* W2  = (const float*)d_in[8];
    const float* as2 = (const float*)d_in[9];
    const float* ad2 = (const float*)d_in[10];
    const float* b2  = (const float*)d_in[11];
    const float* g2  = (const float*)d_in[12];
    const float* be2 = (const float*)d_in[13];
    const float* W3  = (const float*)d_in[14];
    const float* as3 = (const float*)d_in[15];
    const float* ad3 = (const float*)d_in[16];
    const float* b3  = (const float*)d_in[17];

    const int N = in_sizes[0] / 128;
    const int E = in_sizes[1] / 2;

    const int DPB  = cdiv(N, 256);
    const int NBLK = cdiv(E, CSR_CH);

    bf16*     hb    = (bf16*)d_ws;                      // N*128 bf16 (gather table)
    bf16*     aggb  = hb + (size_t)N * 128;             // N*128 bf16 (LN out L1 / h3 L3)
    float*    asrc  = (float*)(aggb + (size_t)N * 128); // N*8
    float*    adst  = asrc + (size_t)N * 8;             // N*8
    float*    asrc3 = adst + (size_t)N * 8;             // N
    float*    adst3 = asrc3 + N;                        // N
    unsigned* pairs = (unsigned*)(adst3 + N);           // 256*REG u32
    int*      col   = (int*)(pairs + 256 * CSR_REG);    // 256*REG
    int2*     ptrSE = (int2*)(col + 256 * CSR_REG);     // N
    int*      histM = (int*)(ptrSE + N);                // NBLK*256
    int*      offT  = histM + (size_t)NBLK * 256;       // 256*NBLK
    int*      btot  = offT + (size_t)NBLK * 256;        // 256
    bf16*     h3b   = aggb;                             // N*16 bf16 (layer 3 logits)

    const int NG1 = cdiv(N, 64);

    // layer-1 GEMM (+alpha) fused with csr_hist blocks
    gemm_mfma<float, 8><<<NG1 + NBLK, 256, 0, stream>>>(
        x, W1, as1, ad1, hb, asrc, adst, N, NG1, ei, E, DPB, histM);
    csr_colscan<<<256, 256, 0, stream>>>(histM, NBLK, offT, btot);
    csr_pair_scatter<<<NBLK, 512, 0, stream>>>(ei, E, DPB, offT, NBLK, pairs);
    csr_fine<<<256, 512, 0, stream>>>(pairs, btot, DPB, N, ptrSE, col);

    // layer 1 aggregation -> LN -> ELU (bf16 out in aggb)
    agg_ln_l1<<<cdiv(N, 16), 256, 0, stream>>>(
        ptrSE, col, asrc, adst, hb, b1, g1, be1, aggb, N);

    // layer 2 GEMM (+alpha), no hist blocks
    const int NG2 = cdiv(N, 64);
    gemm_mfma<bf16, 4><<<NG2, 256, 0, stream>>>(
        aggb, W2, as2, ad2, hb, asrc, adst, N, NG2, nullptr, 0, 1, nullptr);

    // layer 2 aggregation -> LN -> ELU -> fused gemm3 + alpha3 (h3 into aggb)
    agg_ln_l2_g3<<<cdiv(N, 32), 256, 0, stream>>>(
        ptrSE, col, asrc, adst, hb, b2, g2, be2, W3, as3, ad3,
        h3b, asrc3, adst3, N);

    // layer 3 aggregation + bias + log_softmax -> d_out
    agg_l3_final<<<cdiv(N, 64), 256, 0, stream>>>(
        ptrSE, col, asrc3, adst3, h3b, b3, (float*)d_out, N);
}